// Round 1
// baseline (615.606 us; speedup 1.0000x reference)
//
#include <hip/hip_runtime.h>
#include <hip/hip_bf16.h>

typedef short short8 __attribute__((ext_vector_type(8)));
typedef float f32x4 __attribute__((ext_vector_type(4)));
typedef unsigned short u16;
typedef u16 u16x8 __attribute__((ext_vector_type(8)));

#define NL_STRIDE 57344
#define OFF_W1F 0
#define OFF_W2F 16384
#define OFF_W3F 49152
#define OFF_W1K 53248
#define OFF_B1  54272
#define OFF_B2  54784
#define OFF_B3  55296

__device__ __forceinline__ u16 f2bf(float f) {
  union { float f; unsigned int u; } v; v.f = f;
  unsigned int r = v.u + 0x7fffu + ((v.u >> 16) & 1u);
  return (u16)(r >> 16);
}

// gelu(x) = x * Phi_approx(x); Phi ~ 0.5 + x*(p0 + p1*x^2 + p2*x^4), clamped to [0,1].
// Max |err| vs exact erf-GELU ~6e-3 at |x|~2 (preacts are ~N(0,0.16^2), |x|<1.2 in practice).
__device__ __forceinline__ float gelu_fast(float x) {
  float u = x * x;
  float t = fmaf(0.00417617f, u, -0.0560330f);
  t = fmaf(t, u, 0.394326f);
  float s = fmaf(x, t, 0.5f);
  s = __builtin_amdgcn_fmed3f(s, 0.0f, 1.0f);
  return x * s;
}

// ---------------- prep: swizzle fp32 weights -> bf16 MFMA B-fragment order in ws ----
// B-frag layout for mfma_f32_16x16x32_bf16, tile (kt,nt): lane l holds
// B[kt*32 + (l>>4)*8 + j][nt*16 + (l&15)], j=0..7; flat elem = (kt*NT+nt)*512 + l*8 + j.
__global__ __launch_bounds__(256) void prep_kernel(
    const float* __restrict__ sW1, const float* __restrict__ sb1,
    const float* __restrict__ sW2, const float* __restrict__ sb2,
    const float* __restrict__ sW3, const float* __restrict__ sb3,
    const float* __restrict__ tW1, const float* __restrict__ tb1,
    const float* __restrict__ tW2, const float* __restrict__ tb2,
    const float* __restrict__ tW3, const float* __restrict__ tb3,
    char* __restrict__ ws)
{
  int nl = blockIdx.x;               // 0..7 = layer*2 + net
  int layer = nl >> 1, net = nl & 1;
  const float* W1 = net ? tW1 : sW1;
  const float* W2 = net ? tW2 : sW2;
  const float* W3 = net ? tW3 : sW3;
  const float* B1 = net ? tb1 : sb1;
  const float* B2 = net ? tb2 : sb2;
  const float* B3 = net ? tb3 : sb3;
  char* base = ws + (size_t)nl * NL_STRIDE;
  int e = blockIdx.y * 256 + (int)threadIdx.x;

  if (e < 8192) {                                   // W1 (h-rows 2..65): K=64, N=128
    int kt = e >> 12, rem = e & 4095, nt = rem >> 9, r2 = rem & 511;
    int l = r2 >> 3, j = r2 & 7;
    int k = kt * 32 + (l >> 4) * 8 + j, n = nt * 16 + (l & 15);
    ((u16*)(base + OFF_W1F))[e] = f2bf(W1[layer * 8448 + (2 + k) * 128 + n]);
  } else if (e < 24576) {                           // W2: K=128, N=128
    int e2 = e - 8192;
    int kt = e2 >> 12, nt = (e2 >> 9) & 7, l = (e2 >> 3) & 63, j = e2 & 7;
    int k = kt * 32 + (l >> 4) * 8 + j, n = nt * 16 + (l & 15);
    ((u16*)(base + OFF_W2F))[e2] = f2bf(W2[layer * 16384 + k * 128 + n]);
  } else if (e < 26624) {                           // W3: K=128, N padded 2->16
    int e3 = e - 24576;
    int kt = e3 >> 9, l = (e3 >> 3) & 63, j = e3 & 7;
    int k = kt * 32 + (l >> 4) * 8 + j, n = l & 15;
    float v = (n < 2) ? W3[layer * 256 + k * 2 + n] : 0.0f;
    ((u16*)(base + OFF_W3F))[e3] = f2bf(v);
  } else if (e < 26880) {                           // W1 keep-rows 0..1 as fp32 [2][128]
    int e4 = e - 26624; int r = e4 >> 7, n = e4 & 127;
    ((float*)(base + OFF_W1K))[e4] = W1[layer * 8448 + r * 128 + n];
  } else if (e < 27008) {
    int e5 = e - 26880; ((float*)(base + OFF_B1))[e5] = B1[layer * 128 + e5];
  } else if (e < 27136) {
    int e6 = e - 27008; ((float*)(base + OFF_B2))[e6] = B2[layer * 128 + e6];
  } else if (e < 27138) {
    int e7 = e - 27136; ((float*)(base + OFF_B3))[e7] = B3[layer * 2 + e7];
  }
}

// ---------------- main fused kernel: 128 rows/block, 256 threads (4 waves) ----------
__global__ __launch_bounds__(256, 2) void realnvp_kernel(
    const float* __restrict__ theta, const float* __restrict__ h_g,
    const char* __restrict__ ws, float* __restrict__ out)
{
  __shared__ __align__(16) u16 hs[128 * 72];     // h tile, bf16, row stride 72 (16B-aligned rows)
  __shared__ __align__(16) u16 hid[128 * 136];   // hidden, bf16, row stride 136
  __shared__ float x_lds[128 * 4];               // current x, fp32
  __shared__ float sbuf[2 * 128 * 2];            // s/t outputs per net

  const int tid = (int)threadIdx.x;
  const int row0 = (int)blockIdx.x * 128;
  const int wv = tid >> 6, lane = tid & 63, q = lane >> 4, lr = lane & 15;

  // ---- stage theta -> x_lds
  if (tid < 128) {
    float4 t4 = *(const float4*)(theta + (size_t)(row0 + tid) * 4);
    x_lds[tid * 4 + 0] = t4.x; x_lds[tid * 4 + 1] = t4.y;
    x_lds[tid * 4 + 2] = t4.z; x_lds[tid * 4 + 3] = t4.w;
  }
  // ---- stage h -> hs (bf16); thread covers half a row (32 cols)
  {
    int r = tid >> 1, hf = tid & 1;
    const float* src = h_g + (size_t)(row0 + r) * 64 + hf * 32;
    u16* dst = &hs[r * 72 + hf * 32];
#pragma unroll
    for (int c = 0; c < 32; c += 8) {
      float4 f0 = *(const float4*)(src + c);
      float4 f1 = *(const float4*)(src + c + 4);
      u16x8 o;
      o[0] = f2bf(f0.x); o[1] = f2bf(f0.y); o[2] = f2bf(f0.z); o[3] = f2bf(f0.w);
      o[4] = f2bf(f1.x); o[5] = f2bf(f1.y); o[6] = f2bf(f1.z); o[7] = f2bf(f1.w);
      *(u16x8*)(dst + c) = o;
    }
  }
  __syncthreads();

  float logdet = 0.0f;
  const f32x4 zero4 = {0.f, 0.f, 0.f, 0.f};
  const int col0 = wv * 32 + lr;                 // first of the wave's two 16-col tiles

#pragma unroll 1
  for (int layer = 0; layer < 4; ++layer) {
    int k0 = (0x0210 >> (layer * 4)) & 15;       // KEEP[layer][0]
    int k1 = (0x3321 >> (layer * 4)) & 15;       // KEEP[layer][1]

#pragma unroll 1
    for (int net = 0; net < 2; ++net) {
      const char* base = ws + (size_t)(layer * 2 + net) * NL_STRIDE;
      const u16* w1f = (const u16*)(base + OFF_W1F);
      const u16* w2f = (const u16*)(base + OFF_W2F);
      const u16* w3f = (const u16*)(base + OFF_W3F);
      const float* w1k = (const float*)(base + OFF_W1K);
      const float* b1 = (const float*)(base + OFF_B1);
      const float* b2 = (const float*)(base + OFF_B2);
      const float* b3 = (const float*)(base + OFF_B3);

      // ================= GEMM1: hid_pre = h @ W1h  (M=128,N=128,K=64) ================
      f32x4 acc[8][2];
#pragma unroll
      for (int mt = 0; mt < 8; ++mt) { acc[mt][0] = zero4; acc[mt][1] = zero4; }
      {
        const u16* abase = &hs[lr * 72 + q * 8];
#pragma unroll
        for (int kt = 0; kt < 2; ++kt) {
          short8 a[8];
#pragma unroll
          for (int mt = 0; mt < 8; ++mt)
            a[mt] = *(const short8*)(abase + mt * (16 * 72) + kt * 32);
          short8 b0 = *(const short8*)(w1f + (kt * 8 + wv * 2 + 0) * 512 + lane * 8);
          short8 b1v = *(const short8*)(w1f + (kt * 8 + wv * 2 + 1) * 512 + lane * 8);
#pragma unroll
          for (int mt = 0; mt < 8; ++mt) {
            acc[mt][0] = __builtin_amdgcn_mfma_f32_16x16x32_bf16(a[mt], b0, acc[mt][0], 0, 0, 0);
            acc[mt][1] = __builtin_amdgcn_mfma_f32_16x16x32_bf16(a[mt], b1v, acc[mt][1], 0, 0, 0);
          }
        }
      }
      // epilogue: + keep-cols rank-2 + bias, GELU, -> hid (bf16)
      float wk00 = w1k[col0],       wk01 = w1k[col0 + 16];
      float wk10 = w1k[128 + col0], wk11 = w1k[128 + col0 + 16];
      float bb0 = b1[col0], bb1 = b1[col0 + 16];
      __syncthreads();               // prior readers of hid (prev GEMM3) are done
#pragma unroll
      for (int mt = 0; mt < 8; ++mt) {
        int rb = mt * 16 + q * 4;
#pragma unroll
        for (int r = 0; r < 4; ++r) {
          int row = rb + r;
          float xk0 = x_lds[row * 4 + k0], xk1 = x_lds[row * 4 + k1];
          float v0 = acc[mt][0][r] + xk0 * wk00 + xk1 * wk10 + bb0;
          float v1 = acc[mt][1][r] + xk0 * wk01 + xk1 * wk11 + bb1;
          hid[row * 136 + col0]      = f2bf(gelu_fast(v0));
          hid[row * 136 + col0 + 16] = f2bf(gelu_fast(v1));
        }
      }
      __syncthreads();

      // ================= GEMM2: hid = gelu(hid @ W2 + b2)  (K=128, in-place) =========
      f32x4 acc2[8][2];
#pragma unroll
      for (int mt = 0; mt < 8; ++mt) { acc2[mt][0] = zero4; acc2[mt][1] = zero4; }
      {
        const u16* hbase = &hid[lr * 136 + q * 8];
#pragma unroll
        for (int kt = 0; kt < 4; ++kt) {
          short8 a[8];
#pragma unroll
          for (int mt = 0; mt < 8; ++mt)
            a[mt] = *(const short8*)(hbase + mt * (16 * 136) + kt * 32);
          short8 b0 = *(const short8*)(w2f + (kt * 8 + wv * 2 + 0) * 512 + lane * 8);
          short8 b1v = *(const short8*)(w2f + (kt * 8 + wv * 2 + 1) * 512 + lane * 8);
#pragma unroll
          for (int mt = 0; mt < 8; ++mt) {
            acc2[mt][0] = __builtin_amdgcn_mfma_f32_16x16x32_bf16(a[mt], b0, acc2[mt][0], 0, 0, 0);
            acc2[mt][1] = __builtin_amdgcn_mfma_f32_16x16x32_bf16(a[mt], b1v, acc2[mt][1], 0, 0, 0);
          }
        }
      }
      float cb0 = b2[col0], cb1 = b2[col0 + 16];
      __syncthreads();               // all reads of hid done before overwrite
#pragma unroll
      for (int mt = 0; mt < 8; ++mt) {
        int rb = mt * 16 + q * 4;
#pragma unroll
        for (int r = 0; r < 4; ++r) {
          int row = rb + r;
          hid[row * 136 + col0]      = f2bf(gelu_fast(acc2[mt][0][r] + cb0));
          hid[row * 136 + col0 + 16] = f2bf(gelu_fast(acc2[mt][1][r] + cb1));
        }
      }
      __syncthreads();

      // ================= GEMM3: s/t = hid @ W3 + b3  (N padded to 16) ================
      // wave wv covers m-tiles {2wv, 2wv+1}, single n-tile
      f32x4 acc3[2]; acc3[0] = zero4; acc3[1] = zero4;
#pragma unroll
      for (int kt = 0; kt < 4; ++kt) {
        short8 b = *(const short8*)(w3f + kt * 512 + lane * 8);
#pragma unroll
        for (int i = 0; i < 2; ++i) {
          short8 a = *(const short8*)(&hid[((wv * 2 + i) * 16 + lr) * 136 + kt * 32 + q * 8]);
          acc3[i] = __builtin_amdgcn_mfma_f32_16x16x32_bf16(a, b, acc3[i], 0, 0, 0);
        }
      }
      if (lr < 2) {
        float bb = b3[lr];
#pragma unroll
        for (int i = 0; i < 2; ++i) {
          int rb = (wv * 2 + i) * 16 + q * 4;
#pragma unroll
          for (int r = 0; r < 4; ++r)
            sbuf[net * 256 + (rb + r) * 2 + lr] = acc3[i][r] + bb;
        }
      }
      __syncthreads();
    }  // net

    // ================= coupling update =================
    if (tid < 128) {
      float s0 = sbuf[tid * 2 + 0], s1 = sbuf[tid * 2 + 1];
      float t0 = sbuf[256 + tid * 2 + 0], t1 = sbuf[256 + tid * 2 + 1];
      int a0 = (0x1002 >> (layer * 4)) & 15;     // TRANS[layer][0]
      int a1 = (0x2133 >> (layer * 4)) & 15;     // TRANS[layer][1]
      x_lds[tid * 4 + a0] = x_lds[tid * 4 + a0] * __expf(s0) + t0;
      x_lds[tid * 4 + a1] = x_lds[tid * 4 + a1] * __expf(s1) + t1;
      logdet += s0 + s1;
    }
    __syncthreads();
  }  // layer

  if (tid < 128) {
    float x0 = x_lds[tid * 4 + 0], x1 = x_lds[tid * 4 + 1];
    float x2 = x_lds[tid * 4 + 2], x3 = x_lds[tid * 4 + 3];
    out[row0 + tid] = -0.5f * (x0 * x0 + x1 * x1 + x2 * x2 + x3 * x3)
                      - 3.6757541328f + logdet;
  }
}

extern "C" void kernel_launch(void* const* d_in, const int* in_sizes, int n_in,
                              void* d_out, int out_size, void* d_ws, size_t ws_size,
                              hipStream_t stream) {
  (void)in_sizes; (void)n_in; (void)out_size; (void)ws_size;
  const float* theta = (const float*)d_in[0];
  const float* h     = (const float*)d_in[1];
  const float* sW1 = (const float*)d_in[2],  *sb1 = (const float*)d_in[3];
  const float* sW2 = (const float*)d_in[4],  *sb2 = (const float*)d_in[5];
  const float* sW3 = (const float*)d_in[6],  *sb3 = (const float*)d_in[7];
  const float* tW1 = (const float*)d_in[8],  *tb1 = (const float*)d_in[9];
  const float* tW2 = (const float*)d_in[10], *tb2 = (const float*)d_in[11];
  const float* tW3 = (const float*)d_in[12], *tb3 = (const float*)d_in[13];
  float* out = (float*)d_out;
  char* ws = (char*)d_ws;

  dim3 pgrid(8, 107);   // 8 net-layers x ceil(27138/256)
  prep_kernel<<<pgrid, 256, 0, stream>>>(sW1, sb1, sW2, sb2, sW3, sb3,
                                         tW1, tb1, tW2, tb2, tW3, tb3, ws);
  realnvp_kernel<<<4096, 256, 0, stream>>>(theta, h, (const char*)ws, out);
}